// Round 3
// baseline (90.699 us; speedup 1.0000x reference)
//
#include <hip/hip_runtime.h>
#include <hip/hip_bf16.h>

typedef short short8 __attribute__((ext_vector_type(8)));
typedef float floatx4 __attribute__((ext_vector_type(4)));

#define HID 32
#define NTD 8
#define FAN_IN 18

// round-to-nearest-even f32 -> bf16 (bit pattern in a short)
__device__ __forceinline__ short f2bf(float f) {
    union { float f; unsigned u; } v; v.f = f;
    unsigned r = v.u + 0x7fffu + ((v.u >> 16) & 1u);
    return (short)(r >> 16);
}

// packed f32x2 -> bf16x2 (single HW instruction)
__device__ __forceinline__ unsigned cvt_pk_bf16(float lo, float hi) {
    unsigned r;
    asm("v_cvt_pk_bf16_f32 %0, %1, %2" : "=v"(r) : "v"(lo), "v"(hi));
    return r;
}

// sigmoid via hw exp2 + hw rcp (~4 VALU/trans ops)
__device__ __forceinline__ float fast_sigmoid(float x) {
    float e = __builtin_amdgcn_exp2f(x * -1.44269504f);
    return __builtin_amdgcn_rcpf(1.0f + e);
}

// ---------------- table build: T[n] = [emb(8), mask, 1.0, 0x6] as 16 bf16 (32B/row)
__global__ void build_table(const float* __restrict__ emb,
                            const float* __restrict__ mask,
                            short* __restrict__ T, int N) {
    int n = blockIdx.x * blockDim.x + threadIdx.x;
    if (n >= N) return;
    const float4* p = (const float4*)(emb + (size_t)n * NTD);
    float4 lo = p[0], hi = p[1];
    short8 a, b;
    a[0] = f2bf(lo.x); a[1] = f2bf(lo.y); a[2] = f2bf(lo.z); a[3] = f2bf(lo.w);
    a[4] = f2bf(hi.x); a[5] = f2bf(hi.y); a[6] = f2bf(hi.z); a[7] = f2bf(hi.w);
    b[0] = f2bf(mask[n]); b[1] = (short)0x3F80;  // 1.0 bf16 (bias carrier)
    b[2] = b[3] = b[4] = b[5] = b[6] = b[7] = 0;
    short8* row = (short8*)(T + (size_t)n * 16);
    row[0] = a; row[1] = b;
}

// ---------------- index block load (64 edges -> 4 per lane) ----------------
template <int ESZ>
__device__ __forceinline__ int4 load_idx4(const char* __restrict__ sideBase,
                                          long long grp, long long nGroups,
                                          long long E, int r) {
    long long g = (grp < nGroups) ? grp : (nGroups - 1);   // clamp (prefetch safety)
    long long base = g << 6;
    long long e0 = base + 4 * (long long)r;
    int4 v;
    if (base + 64 <= E) {
        if (ESZ == 8) {
            const int4* ip = (const int4*)(sideBase + (size_t)e0 * 8);
            int4 w0 = ip[0], w1 = ip[1];
            v.x = w0.x; v.y = w0.z; v.z = w1.x; v.w = w1.z;
        } else {
            v = *(const int4*)(sideBase + (size_t)e0 * 4);
        }
    } else {
        long long em = E - 1;
        long long ea = e0     < em ? e0     : em;
        long long eb = e0 + 1 < em ? e0 + 1 : em;
        long long ec = e0 + 2 < em ? e0 + 2 : em;
        long long ed = e0 + 3 < em ? e0 + 3 : em;
        v.x = *(const int*)(sideBase + (size_t)ea * ESZ);
        v.y = *(const int*)(sideBase + (size_t)eb * ESZ);
        v.z = *(const int*)(sideBase + (size_t)ec * ESZ);
        v.w = *(const int*)(sideBase + (size_t)ed * ESZ);
    }
    return v;
}

__device__ __forceinline__ short8 gath(const char* __restrict__ Tc, int idx, unsigned halfOff) {
    return *(const short8*)(Tc + ((unsigned)idx * 32u + halfOff));
}

// 3-MFMA edge evaluator: h = relu(W1^T f + b1); logit = W2^T h (valid on g==0 lanes)
__device__ __forceinline__ float edge_logit(short8 a0, short8 a1, short8 a2, short8 fb) {
    floatx4 z = {0.f, 0.f, 0.f, 0.f};
    floatx4 h0 = __builtin_amdgcn_mfma_f32_16x16x32_bf16(a0, fb, z, 0, 0, 0);
    floatx4 h1 = __builtin_amdgcn_mfma_f32_16x16x32_bf16(a1, fb, z, 0, 0, 0);
    unsigned u0 = cvt_pk_bf16(fmaxf(h0[0], 0.f), fmaxf(h0[1], 0.f));
    unsigned u1 = cvt_pk_bf16(fmaxf(h0[2], 0.f), fmaxf(h0[3], 0.f));
    unsigned u2 = cvt_pk_bf16(fmaxf(h1[0], 0.f), fmaxf(h1[1], 0.f));
    unsigned u3 = cvt_pk_bf16(fmaxf(h1[2], 0.f), fmaxf(h1[3], 0.f));
    int4 bu; bu.x = (int)u0; bu.y = (int)u1; bu.z = (int)u2; bu.w = (int)u3;
    short8 b2 = __builtin_bit_cast(short8, bu);
    floatx4 o = __builtin_amdgcn_mfma_f32_16x16x32_bf16(a2, b2, z, 0, 0, 0);
    return o[0];
}

template <int ESZ>
__device__ void run_loop(const char* __restrict__ ei,
                         const char* __restrict__ Tc,
                         float* __restrict__ out, long long E,
                         short8 a0, short8 a1, short8 a2, float bias2,
                         long long waveId, long long nWaves, int g, int r) {
    const long long nGroups = (E + 63) >> 6;
    const char* sideBase = ei + (g >= 2 ? (size_t)E * ESZ : 0);
    const unsigned halfOff = (unsigned)(g & 1) * 16u;

    if (waveId >= nGroups) return;

    long long cur = waveId;
    long long nxt = cur + nWaves;

    int4 ic = load_idx4<ESZ>(sideBase, cur, nGroups, E, r);
    short8 fc0 = gath(Tc, ic.x, halfOff);
    short8 fc1 = gath(Tc, ic.y, halfOff);
    short8 fc2 = gath(Tc, ic.z, halfOff);
    short8 fc3 = gath(Tc, ic.w, halfOff);
    int4 in0 = load_idx4<ESZ>(sideBase, nxt, nGroups, E, r);   // clamped if OOR

    while (true) {
        // --- issue next group's gathers + next-next index load (overlap compute) ---
        short8 fn0 = gath(Tc, in0.x, halfOff);
        short8 fn1 = gath(Tc, in0.y, halfOff);
        short8 fn2 = gath(Tc, in0.z, halfOff);
        short8 fn3 = gath(Tc, in0.w, halfOff);
        int4 in1 = load_idx4<ESZ>(sideBase, nxt + nWaves, nGroups, E, r);

        // --- compute current group (4 x 16 edges) ---
        float v0 = fast_sigmoid(edge_logit(a0, a1, a2, fc0) + bias2);
        float v1 = fast_sigmoid(edge_logit(a0, a1, a2, fc1) + bias2);
        float v2 = fast_sigmoid(edge_logit(a0, a1, a2, fc2) + bias2);
        float v3 = fast_sigmoid(edge_logit(a0, a1, a2, fc3) + bias2);

        long long base = cur << 6;
        if (g == 0) {
            long long e0 = base + 4 * (long long)r;
            if (base + 64 <= E) {
                float4 st; st.x = v0; st.y = v1; st.z = v2; st.w = v3;
                *(float4*)(out + e0) = st;
            } else {
                if (e0     < E) out[e0]     = v0;
                if (e0 + 1 < E) out[e0 + 1] = v1;
                if (e0 + 2 < E) out[e0 + 2] = v2;
                if (e0 + 3 < E) out[e0 + 3] = v3;
            }
        }

        cur = nxt;
        if (cur >= nGroups) break;
        nxt = cur + nWaves;
        fc0 = fn0; fc1 = fn1; fc2 = fn2; fc3 = fn3;
        in0 = in1;
    }
}

__global__ __launch_bounds__(256, 4) void lg_table_kernel(
    const char* __restrict__ ei_bytes,
    const short* __restrict__ T,
    const float* __restrict__ W1,
    const float* __restrict__ b1,
    const float* __restrict__ W2,
    const float* __restrict__ b2,
    float* __restrict__ out,
    long long E)
{
    const int lane = threadIdx.x & 63;
    const int waveInBlock = threadIdx.x >> 6;
    const long long waveId = (long long)blockIdx.x * (blockDim.x >> 6) + waveInBlock;
    const long long nWaves = (long long)gridDim.x * (blockDim.x >> 6);

    // detect edge_index element size: int64 (odd 4B words all zero) vs int32
    const int* ei32 = (const int*)ei_bytes;
    int probe = ei32[2 * lane + 1];
    unsigned long long nz = __ballot(probe != 0);
    const int esz = (nz == 0ull) ? 8 : 4;

    const int r = lane & 15;   // A row / B col
    const int g = lane >> 4;   // k-slice g*8 .. g*8+7

    // A fragments (layer 1): feature map
    //   k0..7 = emb_s -> W1[0..7], k8 = ms -> W1[16], k9 = 1 -> b1, k10..15 = 0
    //   k16..23 = emb_d -> W1[8..15], k24 = md -> W1[17], k25..31 = 0
    short8 a0, a1;
    #pragma unroll
    for (int j = 0; j < 8; ++j) {
        int k = g * 8 + j;
        float v0 = 0.f, v1 = 0.f;
        if (k < 8)                    { v0 = W1[k * HID + r];        v1 = W1[k * HID + 16 + r]; }
        else if (k == 8)              { v0 = W1[16 * HID + r];       v1 = W1[16 * HID + 16 + r]; }
        else if (k == 9)              { v0 = b1[r];                  v1 = b1[16 + r]; }
        else if (k >= 16 && k < 24)   { v0 = W1[(k - 8) * HID + r];  v1 = W1[(k - 8) * HID + 16 + r]; }
        else if (k == 24)             { v0 = W1[17 * HID + r];       v1 = W1[17 * HID + 16 + r]; }
        a0[j] = f2bf(v0);
        a1[j] = f2bf(v1);
    }

    // A fragment (layer 2): A2[row 0][k] = W2[pi(k)], pi maps MFMA-1 C/D rows onto
    // MFMA-2 B k-slots: lane(g,r) holds H rows {g*4+q} (h0) and {16+g*4+q} (h1),
    // and supplies B2 k = g*8+j  (j<4 -> h0[j], j>=4 -> h1[j-4]).
    short8 a2;
    #pragma unroll
    for (int j = 0; j < 8; ++j) {
        int p = (j < 4) ? (g * 4 + j) : (16 + g * 4 + (j - 4));
        a2[j] = (r == 0) ? f2bf(W2[p]) : (short)0;
    }

    const float bias2 = b2[0];

    if (esz == 8)
        run_loop<8>(ei_bytes, (const char*)T, out, E, a0, a1, a2, bias2, waveId, nWaves, g, r);
    else
        run_loop<4>(ei_bytes, (const char*)T, out, E, a0, a1, a2, bias2, waveId, nWaves, g, r);
}

// ---------------- fallback (round-1 kernel, used if d_ws too small) ----------------
__global__ __launch_bounds__(256, 4) void lg_kernel(
    const float* __restrict__ nt_emb,
    const char* __restrict__ ei_bytes,
    const float* __restrict__ lm_mask,
    const float* __restrict__ W1,
    const float* __restrict__ b1,
    const float* __restrict__ W2,
    const float* __restrict__ b2,
    float* __restrict__ out,
    long long E)
{
    const int lane = threadIdx.x & 63;
    const int waveInBlock = threadIdx.x >> 6;
    const long long waveId = (long long)blockIdx.x * (blockDim.x >> 6) + waveInBlock;
    const long long nWaves = (long long)gridDim.x * (blockDim.x >> 6);

    const int* ei32 = (const int*)ei_bytes;
    int probe = ei32[2 * lane + 1];
    unsigned long long nz = __ballot(probe != 0);
    const long long esz = (nz == 0ull) ? 8 : 4;

    const int r = lane & 15;
    const int g = lane >> 4;

    short8 a0, a1;
    #pragma unroll
    for (int j = 0; j < 8; ++j) {
        int k = g * 8 + j;
        float v0 = 0.f, v1 = 0.f;
        if (k < FAN_IN)       { v0 = W1[k * HID + r];      v1 = W1[k * HID + 16 + r]; }
        else if (k == FAN_IN) { v0 = b1[r];                v1 = b1[16 + r]; }
        a0[j] = f2bf(v0);
        a1[j] = f2bf(v1);
    }

    float w2v0[4], w2v1[4];
    #pragma unroll
    for (int q = 0; q < 4; ++q) {
        w2v0[q] = W2[g * 4 + q];
        w2v1[q] = W2[16 + g * 4 + q];
    }
    const float bias2 = b2[0];

    const long long nGroups = (E + 15) >> 4;
    for (long long grp = waveId; grp < nGroups; grp += nWaves) {
        long long e = (grp << 4) + r;
        const bool valid = (e < E);
        long long ec = valid ? e : (E - 1);

        int s = *(const int*)(ei_bytes + ec * esz);
        int d = *(const int*)(ei_bytes + (E + ec) * esz);

        short8 fb;
        #pragma unroll
        for (int j = 0; j < 8; ++j) fb[j] = 0;
        if (g < 2) {
            const float4* p = (const float4*)(nt_emb + (long long)(g == 0 ? s : d) * NTD);
            float4 lo = p[0];
            float4 hi = p[1];
            fb[0] = f2bf(lo.x); fb[1] = f2bf(lo.y); fb[2] = f2bf(lo.z); fb[3] = f2bf(lo.w);
            fb[4] = f2bf(hi.x); fb[5] = f2bf(hi.y); fb[6] = f2bf(hi.z); fb[7] = f2bf(hi.w);
        } else if (g == 2) {
            fb[0] = f2bf(lm_mask[s]);
            fb[1] = f2bf(lm_mask[d]);
            fb[2] = (short)0x3F80;
        }

        floatx4 acc0 = {0.f, 0.f, 0.f, 0.f};
        floatx4 acc1 = {0.f, 0.f, 0.f, 0.f};
        acc0 = __builtin_amdgcn_mfma_f32_16x16x32_bf16(a0, fb, acc0, 0, 0, 0);
        acc1 = __builtin_amdgcn_mfma_f32_16x16x32_bf16(a1, fb, acc1, 0, 0, 0);

        float partial = 0.f;
        #pragma unroll
        for (int q = 0; q < 4; ++q) {
            partial += fmaxf(acc0[q], 0.f) * w2v0[q];
            partial += fmaxf(acc1[q], 0.f) * w2v1[q];
        }
        partial += __shfl_xor(partial, 16, 64);
        partial += __shfl_xor(partial, 32, 64);

        float val = fast_sigmoid(partial + bias2);
        if (g == 0 && valid) out[e] = val;
    }
}

extern "C" void kernel_launch(void* const* d_in, const int* in_sizes, int n_in,
                              void* d_out, int out_size, void* d_ws, size_t ws_size,
                              hipStream_t stream) {
    const float* nt_emb = (const float*)d_in[0];
    const char*  ei     = (const char*)d_in[1];
    const float* lm     = (const float*)d_in[2];
    const float* W1     = (const float*)d_in[3];
    const float* b1     = (const float*)d_in[4];
    const float* W2     = (const float*)d_in[5];
    const float* b2     = (const float*)d_in[6];
    float* out = (float*)d_out;

    long long E = (long long)in_sizes[1] / 2;   // edge_index is [2, E]
    int N = in_sizes[2];                        // lm_mask is [N]

    size_t tableBytes = (size_t)N * 32;
    if (ws_size >= tableBytes) {
        short* T = (short*)d_ws;
        build_table<<<dim3((N + 255) / 256), dim3(256), 0, stream>>>(nt_emb, lm, T, N);
        lg_table_kernel<<<dim3(2048), dim3(256), 0, stream>>>(ei, T, W1, b1, W2, b2, out, E);
    } else {
        lg_kernel<<<dim3(2048), dim3(256), 0, stream>>>(nt_emb, ei, lm, W1, b1, W2, b2, out, E);
    }
}

// Round 4
// 77.236 us; speedup vs baseline: 1.1743x; 1.1743x over previous
//
#include <hip/hip_runtime.h>
#include <hip/hip_bf16.h>

typedef short short8 __attribute__((ext_vector_type(8)));
typedef float floatx4 __attribute__((ext_vector_type(4)));
typedef float floatx16 __attribute__((ext_vector_type(16)));

#define HID 32
#define NTD 8
#define FAN_IN 18

// round-to-nearest-even f32 -> bf16 (bit pattern in a short)
__device__ __forceinline__ short f2bf(float f) {
    union { float f; unsigned u; } v; v.f = f;
    unsigned r = v.u + 0x7fffu + ((v.u >> 16) & 1u);
    return (short)(r >> 16);
}

// sigmoid via hw exp2 + hw rcp
__device__ __forceinline__ float fast_sigmoid(float x) {
    float e = __builtin_amdgcn_exp2f(x * -1.44269504f);
    return __builtin_amdgcn_rcpf(1.0f + e);
}

// ---------------- table build: T[n] = [emb(8), mask, 1.0, 0x6] as 16 bf16 (32B/row)
// s-half (bytes 0..15):  k0..7 = emb        ; d-half is the same 16B at +16? No:
// each node row is 32B: bytes 0..15 = [emb0..7] (k-half 0), bytes 16..31 = [mask,1,0x6] (k-half 1).
__global__ void build_table(const float* __restrict__ emb,
                            const float* __restrict__ mask,
                            short* __restrict__ T, int N) {
    int n = blockIdx.x * blockDim.x + threadIdx.x;
    if (n >= N) return;
    const float4* p = (const float4*)(emb + (size_t)n * NTD);
    float4 lo = p[0], hi = p[1];
    short8 a, b;
    a[0] = f2bf(lo.x); a[1] = f2bf(lo.y); a[2] = f2bf(lo.z); a[3] = f2bf(lo.w);
    a[4] = f2bf(hi.x); a[5] = f2bf(hi.y); a[6] = f2bf(hi.z); a[7] = f2bf(hi.w);
    b[0] = f2bf(mask[n]); b[1] = (short)0x3F80;  // 1.0 bf16 (bias carrier)
    b[2] = b[3] = b[4] = b[5] = b[6] = b[7] = 0;
    short8* row = (short8*)(T + (size_t)n * 16);
    row[0] = a; row[1] = b;
}

// ---------------- main kernel (32x32x16 MFMA, 64 edges / iteration) ----------------
struct IdxQ { unsigned sA, dA, sB, dB; };

template <int ESZ>
__device__ __forceinline__ IdxQ load_idx(const char* __restrict__ sBase,
                                         const char* __restrict__ dBase,
                                         unsigned grp, unsigned nGroups,
                                         unsigned E, unsigned c) {
    unsigned g = grp < nGroups ? grp : nGroups - 1u;   // clamp (prefetch safety)
    unsigned eA = g * 64u + c;
    unsigned eB = eA + 32u;
    if (eA >= E) eA = E - 1u;
    if (eB >= E) eB = E - 1u;
    IdxQ q;
    q.sA = *(const unsigned*)(sBase + eA * (unsigned)ESZ);
    q.dA = *(const unsigned*)(dBase + eA * (unsigned)ESZ);
    q.sB = *(const unsigned*)(sBase + eB * (unsigned)ESZ);
    q.dB = *(const unsigned*)(dBase + eB * (unsigned)ESZ);
    return q;
}

__device__ __forceinline__ short8 g16(const char* __restrict__ Tc, unsigned idx, unsigned hoff) {
    return *(const short8*)(Tc + (idx * 32u + hoff));
}

template <int ESZ>
__device__ void run32(const char* __restrict__ ei,
                      const char* __restrict__ Tc,
                      float* __restrict__ out, unsigned E,
                      short8 as, short8 ad, const float* __restrict__ w2r, float bias2,
                      unsigned waveId, unsigned nWaves, int h, int c, int lane) {
    const unsigned nGroups = (E + 63u) >> 6;
    const char* sBase = ei;
    const char* dBase = ei + (size_t)E * ESZ;
    const unsigned hoff = (unsigned)h * 16u;

    if (waveId >= nGroups) return;

    unsigned cur = waveId;
    const unsigned stride2 = 2u * nWaves;

    IdxQ i0 = load_idx<ESZ>(sBase, dBase, cur, nGroups, E, (unsigned)c);
    short8 bsA = g16(Tc, i0.sA, hoff);
    short8 bdA = g16(Tc, i0.dA, hoff);
    short8 bsB = g16(Tc, i0.sB, hoff);
    short8 bdB = g16(Tc, i0.dB, hoff);
    IdxQ i1 = load_idx<ESZ>(sBase, dBase, cur + nWaves, nGroups, E, (unsigned)c);

    while (true) {
        // prefetch: next group's gathers + next-next indices (overlap with compute)
        short8 nsA = g16(Tc, i1.sA, hoff);
        short8 ndA = g16(Tc, i1.dA, hoff);
        short8 nsB = g16(Tc, i1.sB, hoff);
        short8 ndB = g16(Tc, i1.dB, hoff);
        IdxQ i2 = load_idx<ESZ>(sBase, dBase, cur + stride2, nGroups, E, (unsigned)c);

        // ---- layer 1: two 32-edge tiles, 2 MFMAs each (s-half K + d-half K) ----
        floatx16 accA = {0.f,0.f,0.f,0.f,0.f,0.f,0.f,0.f,0.f,0.f,0.f,0.f,0.f,0.f,0.f,0.f};
        floatx16 accB = accA;
        accA = __builtin_amdgcn_mfma_f32_32x32x16_bf16(as, bsA, accA, 0, 0, 0);
        accB = __builtin_amdgcn_mfma_f32_32x32x16_bf16(as, bsB, accB, 0, 0, 0);
        accA = __builtin_amdgcn_mfma_f32_32x32x16_bf16(ad, bdA, accA, 0, 0, 0);
        accB = __builtin_amdgcn_mfma_f32_32x32x16_bf16(ad, bdB, accB, 0, 0, 0);

        // ---- layer 2: lane(h,c) holds H rows (q&3)+8*(q>>2)+4h of its edge ----
        float pA0 = 0.f, pA1 = 0.f, pB0 = 0.f, pB1 = 0.f;
        #pragma unroll
        for (int q = 0; q < 16; q += 2) {
            pA0 += fmaxf(accA[q],     0.f) * w2r[q];
            pA1 += fmaxf(accA[q + 1], 0.f) * w2r[q + 1];
            pB0 += fmaxf(accB[q],     0.f) * w2r[q];
            pB1 += fmaxf(accB[q + 1], 0.f) * w2r[q + 1];
        }
        float pA = pA0 + pA1;
        float pB = pB0 + pB1;
        pA += __shfl_xor(pA, 32, 64);   // combine the two h-halves (rows 0..31 complete)
        pB += __shfl_xor(pB, 32, 64);
        float vA = fast_sigmoid(pA + bias2);
        float vB = fast_sigmoid(pB + bias2);

        // lane l stores edge base64 + l  (l<32 -> tile A col l, l>=32 -> tile B col l-32)
        float v = (h == 0) ? vA : vB;
        unsigned base = cur << 6;
        unsigned e = base + (unsigned)lane;
        if (base + 64u <= E) {
            out[e] = v;
        } else if (e < E) {
            out[e] = v;
        }

        cur += nWaves;
        if (cur >= nGroups) break;
        bsA = nsA; bdA = ndA; bsB = nsB; bdB = ndB;
        i1 = i2;
    }
}

__global__ __launch_bounds__(256, 4) void lg_table_kernel(
    const char* __restrict__ ei_bytes,
    const short* __restrict__ T,
    const float* __restrict__ W1,
    const float* __restrict__ b1,
    const float* __restrict__ W2,
    const float* __restrict__ b2,
    float* __restrict__ out,
    long long E)
{
    const int lane = threadIdx.x & 63;
    const int waveInBlock = threadIdx.x >> 6;
    const unsigned waveId = (unsigned)(blockIdx.x * (blockDim.x >> 6) + waveInBlock);
    const unsigned nWaves = (unsigned)(gridDim.x * (blockDim.x >> 6));

    // detect edge_index element size: int64 (odd 4B words all zero) vs int32
    const int* ei32 = (const int*)ei_bytes;
    int probe = ei32[2 * lane + 1];
    unsigned long long nz = __ballot(probe != 0);
    const int esz = (nz == 0ull) ? 8 : 4;

    const int c = lane & 31;   // B col / A row index
    const int h = lane >> 5;   // k-half: k = 8h + j

    // A fragments (32x32x16): A[row=c][k=8h+j]
    // s-MFMA: k0..7 = W1 rows 0..7 (emb_s), k8 = W1 row 16 (mask_s), k9 = b1, k10..15 = 0
    // d-MFMA: k0..7 = W1 rows 8..15 (emb_d), k8 = W1 row 17 (mask_d), k9..15 = 0
    short8 as, ad;
    #pragma unroll
    for (int j = 0; j < 8; ++j) {
        float vs = 0.f, vd = 0.f;
        if (h == 0) {
            vs = W1[j * HID + c];
            vd = W1[(8 + j) * HID + c];
        } else {
            if (j == 0) { vs = W1[16 * HID + c]; vd = W1[17 * HID + c]; }
            else if (j == 1) { vs = b1[c]; }
        }
        as[j] = f2bf(vs);
        ad[j] = f2bf(vd);
    }

    // W2 for the 16 H-rows this lane's acc regs hold: row(q) = (q&3) + 8*(q>>2) + 4h
    float w2r[16];
    #pragma unroll
    for (int q = 0; q < 16; ++q)
        w2r[q] = W2[(q & 3) + 8 * (q >> 2) + 4 * h];

    const float bias2 = b2[0];

    if (esz == 8)
        run32<8>(ei_bytes, (const char*)T, out, (unsigned)E, as, ad, w2r, bias2,
                 waveId, nWaves, h, c, lane);
    else
        run32<4>(ei_bytes, (const char*)T, out, (unsigned)E, as, ad, w2r, bias2,
                 waveId, nWaves, h, c, lane);
}

// ---------------- fallback (round-1 kernel, used if d_ws too small) ----------------
__global__ __launch_bounds__(256, 4) void lg_kernel(
    const float* __restrict__ nt_emb,
    const char* __restrict__ ei_bytes,
    const float* __restrict__ lm_mask,
    const float* __restrict__ W1,
    const float* __restrict__ b1,
    const float* __restrict__ W2,
    const float* __restrict__ b2,
    float* __restrict__ out,
    long long E)
{
    const int lane = threadIdx.x & 63;
    const int waveInBlock = threadIdx.x >> 6;
    const long long waveId = (long long)blockIdx.x * (blockDim.x >> 6) + waveInBlock;
    const long long nWaves = (long long)gridDim.x * (blockDim.x >> 6);

    const int* ei32 = (const int*)ei_bytes;
    int probe = ei32[2 * lane + 1];
    unsigned long long nz = __ballot(probe != 0);
    const long long esz = (nz == 0ull) ? 8 : 4;

    const int r = lane & 15;
    const int g = lane >> 4;

    short8 a0, a1;
    #pragma unroll
    for (int j = 0; j < 8; ++j) {
        int k = g * 8 + j;
        float v0 = 0.f, v1 = 0.f;
        if (k < FAN_IN)       { v0 = W1[k * HID + r];      v1 = W1[k * HID + 16 + r]; }
        else if (k == FAN_IN) { v0 = b1[r];                v1 = b1[16 + r]; }
        a0[j] = f2bf(v0);
        a1[j] = f2bf(v1);
    }

    float w2v0[4], w2v1[4];
    #pragma unroll
    for (int q = 0; q < 4; ++q) {
        w2v0[q] = W2[g * 4 + q];
        w2v1[q] = W2[16 + g * 4 + q];
    }
    const float bias2 = b2[0];

    const long long nGroups = (E + 15) >> 4;
    for (long long grp = waveId; grp < nGroups; grp += nWaves) {
        long long e = (grp << 4) + r;
        const bool valid = (e < E);
        long long ec = valid ? e : (E - 1);

        int s = *(const int*)(ei_bytes + ec * esz);
        int d = *(const int*)(ei_bytes + (E + ec) * esz);

        short8 fb;
        #pragma unroll
        for (int j = 0; j < 8; ++j) fb[j] = 0;
        if (g < 2) {
            const float4* p = (const float4*)(nt_emb + (long long)(g == 0 ? s : d) * NTD);
            float4 lo = p[0];
            float4 hi = p[1];
            fb[0] = f2bf(lo.x); fb[1] = f2bf(lo.y); fb[2] = f2bf(lo.z); fb[3] = f2bf(lo.w);
            fb[4] = f2bf(hi.x); fb[5] = f2bf(hi.y); fb[6] = f2bf(hi.z); fb[7] = f2bf(hi.w);
        } else if (g == 2) {
            fb[0] = f2bf(lm_mask[s]);
            fb[1] = f2bf(lm_mask[d]);
            fb[2] = (short)0x3F80;
        }

        floatx4 acc0 = {0.f, 0.f, 0.f, 0.f};
        floatx4 acc1 = {0.f, 0.f, 0.f, 0.f};
        acc0 = __builtin_amdgcn_mfma_f32_16x16x32_bf16(a0, fb, acc0, 0, 0, 0);
        acc1 = __builtin_amdgcn_mfma_f32_16x16x32_bf16(a1, fb, acc1, 0, 0, 0);

        float partial = 0.f;
        #pragma unroll
        for (int q = 0; q < 4; ++q) {
            partial += fmaxf(acc0[q], 0.f) * w2v0[q];
            partial += fmaxf(acc1[q], 0.f) * w2v1[q];
        }
        partial += __shfl_xor(partial, 16, 64);
        partial += __shfl_xor(partial, 32, 64);

        float val = fast_sigmoid(partial + bias2);
        if (g == 0 && valid) out[e] = val;
    }
}

extern "C" void kernel_launch(void* const* d_in, const int* in_sizes, int n_in,
                              void* d_out, int out_size, void* d_ws, size_t ws_size,
                              hipStream_t stream) {
    const float* nt_emb = (const float*)d_in[0];
    const char*  ei     = (const char*)d_in[1];
    const float* lm     = (const float*)d_in[2];
    const float* W1     = (const float*)d_in[3];
    const float* b1     = (const float*)d_in[4];
    const float* W2     = (const float*)d_in[5];
    const float* b2     = (const float*)d_in[6];
    float* out = (float*)d_out;

    long long E = (long long)in_sizes[1] / 2;   // edge_index is [2, E]
    int N = in_sizes[2];                        // lm_mask is [N]

    size_t tableBytes = (size_t)N * 32;
    if (ws_size >= tableBytes) {
        short* T = (short*)d_ws;
        build_table<<<dim3((N + 255) / 256), dim3(256), 0, stream>>>(nt_emb, lm, T, N);
        lg_table_kernel<<<dim3(2048), dim3(256), 0, stream>>>(ei, T, W1, b1, W2, b2, out, E);
    } else {
        lg_kernel<<<dim3(2048), dim3(256), 0, stream>>>(nt_emb, ei, lm, W1, b1, W2, b2, out, E);
    }
}